// Round 1
// baseline (1080.287 us; speedup 1.0000x reference)
//
#include <hip/hip_runtime.h>
#include <hip/hip_bf16.h>

#define B_ 8
#define S_ 2048
#define F_ 1024
#define D_ 1024

typedef unsigned short u16;
typedef float f32x4 __attribute__((ext_vector_type(4)));
typedef __bf16 bf16x8 __attribute__((ext_vector_type(8)));

__device__ __forceinline__ u16 f2bf(float f) {
  union { float f; unsigned u; } v; v.f = f;
  unsigned r = v.u + 0x7fff + ((v.u >> 16) & 1);
  return (u16)(r >> 16);
}
__device__ __forceinline__ float bf2f(u16 b) {
  union { unsigned u; float f; } v; v.u = ((unsigned)b) << 16;
  return v.f;
}

__device__ __forceinline__ void stage16(const u16* g, u16* l) {
  __builtin_amdgcn_global_load_lds(
      (const __attribute__((address_space(1))) void*)g,
      (__attribute__((address_space(3))) void*)l, 16, 0, 0);
}

// ---------------- prep kernels ----------------

__global__ void cast_x(const float* __restrict__ x, u16* __restrict__ xb, int n4) {
  int i = blockIdx.x * blockDim.x + threadIdx.x;
  int stride = gridDim.x * blockDim.x;
  for (; i < n4; i += stride) {
    float4 v = ((const float4*)x)[i];
    ushort4 o;
    o.x = f2bf(v.x); o.y = f2bf(v.y); o.z = f2bf(v.z); o.w = f2bf(v.w);
    ((ushort4*)xb)[i] = o;
  }
}

__global__ void transW(const float* __restrict__ Wq, const float* __restrict__ Wk,
                       const float* __restrict__ Wv, u16* __restrict__ Wt) {
  __shared__ float tile[32][33];
  int z = blockIdx.z;
  const float* W = (z == 0) ? Wq : ((z == 1) ? Wk : Wv);
  int f0 = blockIdx.y * 32, d0 = blockIdx.x * 32;
  int tx = threadIdx.x & 31, ty = threadIdx.x >> 5;
  for (int i = 0; i < 4; i++)
    tile[ty + i * 8][tx] = W[(size_t)(f0 + ty + i * 8) * D_ + d0 + tx];
  __syncthreads();
  u16* o = Wt + (size_t)z * D_ * F_;
  for (int i = 0; i < 4; i++)
    o[(size_t)(d0 + ty + i * 8) * F_ + f0 + tx] = f2bf(tile[tx][ty + i * 8]);
}

// row sums of exp(r - 16) over kept positions (shift-invariant softmax denom)
__global__ void r_rowsum(const float* __restrict__ r, const float* __restrict__ am,
                         const float* __restrict__ pm, float* __restrict__ rs) {
  int row = blockIdx.x;            // b*S + s
  int b = row >> 11, s = row & 2047;
  const float* rp = r + (size_t)row * S_;
  const float* amp = am + (size_t)s * S_;
  const float* pmp = pm + (size_t)b * S_;
  float acc = 0.f;
  for (int t = threadIdx.x; t < S_; t += 256) {
    bool keep = (amp[t] != 0.f) && (pmp[t] != 0.f);
    if (keep) acc += __expf(rp[t] - 16.f);
  }
  for (int off = 1; off < 64; off <<= 1) acc += __shfl_xor(acc, off);
  __shared__ float wsum[4];
  int lane = threadIdx.x & 63, w = threadIdx.x >> 6;
  if (lane == 0) wsum[w] = acc;
  __syncthreads();
  if (threadIdx.x == 0) rs[row] = wsum[0] + wsum[1] + wsum[2] + wsum[3];
}

// ---------------- GEMM core: 128x128 tile, BK=32, 4 waves, 16x16x32 bf16 MFMA ----------------
// A: [M][K] row-major bf16 (lda=K elems). B: [N][K] row-major bf16 ("B^T" layout).
__device__ __forceinline__ void gemm_tile(const u16* __restrict__ Abase, int lda,
                                          const u16* __restrict__ Bbase, int ldb,
                                          int kTiles, u16* As, u16* Bs,
                                          f32x4 acc[4][4]) {
  int t = threadIdx.x;
  int w = t >> 6, l = t & 63;
  int wr = w >> 1, wc = w & 1;
  // staging: tile is [128][32] bf16 = 8192B; 256 thr x 16B x 2 iters
  int bo0 = t * 16;
  int r0 = bo0 >> 6, c0 = bo0 & 63;
  int bo1 = 4096 + t * 16;
  int r1 = bo1 >> 6, c1 = bo1 & 63;
  const u16* a0 = Abase + (size_t)r0 * lda + (c0 >> 1);
  const u16* a1 = Abase + (size_t)r1 * lda + (c1 >> 1);
  const u16* b0 = Bbase + (size_t)r0 * ldb + (c0 >> 1);
  const u16* b1 = Bbase + (size_t)r1 * ldb + (c1 >> 1);
  u16* lA0 = As + (bo0 >> 1); u16* lA1 = As + (bo1 >> 1);
  u16* lB0 = Bs + (bo0 >> 1); u16* lB1 = Bs + (bo1 >> 1);

  for (int m = 0; m < 4; m++)
    for (int n = 0; n < 4; n++)
      for (int j = 0; j < 4; j++) acc[m][n][j] = 0.f;

  int arow = wr * 64 + (l & 15);
  int brow = wc * 64 + (l & 15);
  int koff = (l >> 4) * 8;

  for (int kt = 0; kt < kTiles; kt++) {
    __syncthreads();                       // previous compute done; LDS reusable
    stage16(a0 + kt * 32, lA0);
    stage16(a1 + kt * 32, lA1);
    stage16(b0 + kt * 32, lB0);
    stage16(b1 + kt * 32, lB1);
    __syncthreads();                       // staging drained (vmcnt(0) before barrier)
    bf16x8 af[4], bq[4];
    for (int m = 0; m < 4; m++)
      af[m] = *(const bf16x8*)&As[(arow + m * 16) * 32 + koff];
    for (int n = 0; n < 4; n++)
      bq[n] = *(const bf16x8*)&Bs[(brow + n * 16) * 32 + koff];
    for (int m = 0; m < 4; m++)
      for (int n = 0; n < 4; n++)
        acc[m][n] = __builtin_amdgcn_mfma_f32_16x16x32_bf16(af[m], bq[n], acc[m][n], 0, 0, 0);
  }
}

// ---------------- projection GEMM: q,k row-major; v transposed ----------------
__global__ __launch_bounds__(256) void gemm_qkv(
    const u16* __restrict__ xb, const u16* __restrict__ Wt,
    u16* __restrict__ qb, u16* __restrict__ kb, u16* __restrict__ vT) {
  __shared__ __align__(16) u16 As[128 * 32], Bs[128 * 32];
  int mt = blockIdx.x, nt = blockIdx.y, z = blockIdx.z;
  int m0 = mt * 128, n0 = nt * 128;
  const u16* A = xb + (size_t)m0 * F_;
  const u16* Bb = Wt + (size_t)z * D_ * F_ + (size_t)n0 * F_;
  f32x4 acc[4][4];
  gemm_tile(A, F_, Bb, F_, F_ / 32, As, Bs, acc);
  int t = threadIdx.x, w = t >> 6, l = t & 63;
  int wr = w >> 1, wc = w & 1;
  int rbase = m0 + wr * 64 + ((l >> 4) << 2);
  int cbase = n0 + wc * 64 + (l & 15);
  if (z < 2) {
    u16* out = (z == 0) ? qb : kb;
    for (int m = 0; m < 4; m++)
      for (int j = 0; j < 4; j++) {
        int row = rbase + m * 16 + j;
        for (int n = 0; n < 4; n++)
          out[(size_t)row * D_ + cbase + n * 16] = f2bf(acc[m][n][j]);
      }
  } else {
    for (int m = 0; m < 4; m++)
      for (int j = 0; j < 4; j++) {
        int row = rbase + m * 16 + j;     // row = b*S + s
        int b = row >> 11, s = row & 2047;
        u16* o = vT + (size_t)b * D_ * S_;
        for (int n = 0; n < 4; n++)
          o[(size_t)(cbase + n * 16) * S_ + s] = f2bf(acc[m][n][j]);
      }
  }
}

// ---------------- scores: P = exp(qk/32 + r_sm - 16) (masked), partial row sums ----------------
__global__ __launch_bounds__(256) void attn_scores(
    const u16* __restrict__ qb, const u16* __restrict__ kb,
    const float* __restrict__ r_mat, const float* __restrict__ am,
    const float* __restrict__ pm, const float* __restrict__ rs_r,
    u16* __restrict__ P, float* __restrict__ rowsum) {
  int mt = blockIdx.x, nt = blockIdx.y, b = blockIdx.z;
  if (nt > mt) return;                    // fully above causal diagonal
  __shared__ __align__(16) u16 As[128 * 32], Bs[128 * 32];
  int m0 = mt * 128, n0 = nt * 128;
  const u16* A = qb + ((size_t)b * S_ + m0) * D_;
  const u16* Bb = kb + ((size_t)b * S_ + n0) * D_;
  f32x4 acc[4][4];
  gemm_tile(A, D_, Bb, D_, D_ / 32, As, Bs, acc);
  int t = threadIdx.x, w = t >> 6, l = t & 63;
  int wr = w >> 1, wc = w & 1;
  u16* Pb = P + (size_t)b * S_ * S_;
  const float* rb = r_mat + (size_t)b * S_ * S_;
  const float* pmp = pm + (size_t)b * S_;
  for (int m = 0; m < 4; m++)
    for (int j = 0; j < 4; j++) {
      int s = m0 + wr * 64 + m * 16 + ((l >> 4) << 2) + j;
      float invr = 1.f / rs_r[b * S_ + s];
      const float* rrow = rb + (size_t)s * S_;
      const float* arow_m = am + (size_t)s * S_;
      u16* prow = Pb + (size_t)s * S_;
      float rsum = 0.f;
      for (int n = 0; n < 4; n++) {
        int tc = n0 + wc * 64 + n * 16 + (l & 15);
        bool keep = (arow_m[tc] != 0.f) && (pmp[tc] != 0.f);
        float lg = acc[m][n][j] * (1.f / 32.f) + __expf(rrow[tc] - 16.f) * invr;
        float e = keep ? __expf(lg - 16.f) : 0.f;
        u16 eb = f2bf(e);
        prow[tc] = eb;
        rsum += bf2f(eb);
      }
      for (int off = 1; off < 16; off <<= 1) rsum += __shfl_xor(rsum, off);
      if ((l & 15) == 0) atomicAdd(&rowsum[b * S_ + s], rsum);
    }
}

// ---------------- PV: out = (P @ V) / rowsum ----------------
__global__ __launch_bounds__(256) void attn_pv(
    const u16* __restrict__ P, const u16* __restrict__ vT,
    const float* __restrict__ rowsum, float* __restrict__ out) {
  __shared__ __align__(16) u16 As[128 * 32], Bs[128 * 32];
  int mt = blockIdx.x, dt = blockIdx.y, b = blockIdx.z;
  int m0 = mt * 128, n0 = dt * 128;
  int padlim = (b >= B_ / 2) ? (S_ - 128) : S_;
  int kmax = m0 + 128; if (kmax > padlim) kmax = padlim;
  const u16* A = P + ((size_t)b * S_ + m0) * S_;
  const u16* Bb = vT + ((size_t)b * D_ + n0) * S_;
  f32x4 acc[4][4];
  gemm_tile(A, S_, Bb, S_, kmax / 32, As, Bs, acc);
  int t = threadIdx.x, w = t >> 6, l = t & 63;
  int wr = w >> 1, wc = w & 1;
  int rbase = m0 + wr * 64 + ((l >> 4) << 2);
  int cbase = n0 + wc * 64 + (l & 15);
  for (int m = 0; m < 4; m++)
    for (int j = 0; j < 4; j++) {
      int s = rbase + m * 16 + j;
      float inv = 1.f / rowsum[b * S_ + s];
      float* orow = out + ((size_t)b * S_ + s) * D_;
      for (int n = 0; n < 4; n++)
        orow[cbase + n * 16] = acc[m][n][j] * inv;
    }
}

// ---------------- launch ----------------
extern "C" void kernel_launch(void* const* d_in, const int* in_sizes, int n_in,
                              void* d_out, int out_size, void* d_ws, size_t ws_size,
                              hipStream_t stream) {
  const float* x     = (const float*)d_in[0];
  const float* r_mat = (const float*)d_in[1];
  const float* am    = (const float*)d_in[2];
  const float* pm    = (const float*)d_in[3];
  const float* Wq    = (const float*)d_in[4];
  const float* Wk    = (const float*)d_in[5];
  const float* Wv    = (const float*)d_in[6];
  float* out = (float*)d_out;
  char* ws = (char*)d_ws;

  u16*   qb     = (u16*)(ws + 0);
  u16*   kb     = (u16*)(ws + 33554432ULL);
  u16*   vT     = (u16*)(ws + 67108864ULL);
  float* rs_r   = (float*)(ws + 100663296ULL);
  float* rowsum = (float*)(ws + 100728832ULL);
  u16*   P      = (u16*)(ws + 100794368ULL);   // aliases xb+Wt region (dead by then)
  u16*   xb     = (u16*)(ws + 100794368ULL);
  u16*   Wt     = (u16*)(ws + 134348800ULL);

  cast_x<<<dim3(2048), dim3(256), 0, stream>>>(x, xb, (B_ * S_ * F_) / 4);
  transW<<<dim3(32, 32, 3), dim3(256), 0, stream>>>(Wq, Wk, Wv, Wt);
  r_rowsum<<<dim3(B_ * S_), dim3(256), 0, stream>>>(r_mat, am, pm, rs_r);
  gemm_qkv<<<dim3(128, 8, 3), dim3(256), 0, stream>>>(xb, Wt, qb, kb, vT);
  hipMemsetAsync(rowsum, 0, B_ * S_ * sizeof(float), stream);
  attn_scores<<<dim3(16, 16, 8), dim3(256), 0, stream>>>(qb, kb, r_mat, am, pm, rs_r, P, rowsum);
  attn_pv<<<dim3(16, 8, 8), dim3(256), 0, stream>>>(P, vT, rowsum, out);
}

// Round 2
// 480.201 us; speedup vs baseline: 2.2497x; 2.2497x over previous
//
#include <hip/hip_runtime.h>
#include <hip/hip_bf16.h>

#define B_ 8
#define S_ 2048
#define F_ 1024
#define D_ 1024

typedef unsigned short u16;
typedef float f32x4 __attribute__((ext_vector_type(4)));
typedef __bf16 bf16x8 __attribute__((ext_vector_type(8)));

__device__ __forceinline__ u16 f2bf(float f) {
  union { float f; unsigned u; } v; v.f = f;
  unsigned r = v.u + 0x7fff + ((v.u >> 16) & 1);
  return (u16)(r >> 16);
}
__device__ __forceinline__ float bf2f(u16 b) {
  union { unsigned u; float f; } v; v.u = ((unsigned)b) << 16;
  return v.f;
}

__device__ __forceinline__ void stage16(const u16* g, u16* l) {
  __builtin_amdgcn_global_load_lds(
      (const __attribute__((address_space(1))) void*)g,
      (__attribute__((address_space(3))) void*)l, 16, 0, 0);
}

// ---------------- prep kernels ----------------

__global__ void cast_x(const float* __restrict__ x, u16* __restrict__ xb, int n4) {
  int i = blockIdx.x * blockDim.x + threadIdx.x;
  int stride = gridDim.x * blockDim.x;
  for (; i < n4; i += stride) {
    float4 v = ((const float4*)x)[i];
    ushort4 o;
    o.x = f2bf(v.x); o.y = f2bf(v.y); o.z = f2bf(v.z); o.w = f2bf(v.w);
    ((ushort4*)xb)[i] = o;
  }
}

__global__ void transW(const float* __restrict__ Wq, const float* __restrict__ Wk,
                       const float* __restrict__ Wv, u16* __restrict__ Wt) {
  __shared__ float tile[32][33];
  int z = blockIdx.z;
  const float* W = (z == 0) ? Wq : ((z == 1) ? Wk : Wv);
  int f0 = blockIdx.y * 32, d0 = blockIdx.x * 32;
  int tx = threadIdx.x & 31, ty = threadIdx.x >> 5;
  for (int i = 0; i < 4; i++)
    tile[ty + i * 8][tx] = W[(size_t)(f0 + ty + i * 8) * D_ + d0 + tx];
  __syncthreads();
  u16* o = Wt + (size_t)z * D_ * F_;
  for (int i = 0; i < 4; i++)
    o[(size_t)(d0 + ty + i * 8) * F_ + f0 + tx] = f2bf(tile[tx][ty + i * 8]);
}

// row sums of exp(r - 16) over kept positions (causal: t<=s; pad from memory)
__global__ __launch_bounds__(256) void r_rowsum(const float* __restrict__ r,
                                                const float* __restrict__ pm,
                                                float* __restrict__ rs) {
  int row = blockIdx.x;            // b*S + s
  int b = row >> 11, s = row & 2047;
  const float4* rp = (const float4*)(r + (size_t)row * S_);
  const float4* pp = (const float4*)(pm + (size_t)b * S_);
  int nv = (s >> 2) + 1;           // float4 quads covering t <= s
  float acc = 0.f;
  for (int i = threadIdx.x; i < nv; i += 256) {
    float4 rv = rp[i];
    float4 pv = pp[i];
    int t0 = i << 2;
    #pragma unroll
    for (int j = 0; j < 4; j++) {
      int t = t0 + j;
      if (t <= s && (&pv.x)[j] != 0.f) acc += __expf((&rv.x)[j] - 16.f);
    }
  }
  for (int off = 1; off < 64; off <<= 1) acc += __shfl_xor(acc, off);
  __shared__ float wsum[4];
  int lane = threadIdx.x & 63, w = threadIdx.x >> 6;
  if (lane == 0) wsum[w] = acc;
  __syncthreads();
  if (threadIdx.x == 0) rs[row] = wsum[0] + wsum[1] + wsum[2] + wsum[3];
}

// ---------------- GEMM core: 128x128 tile, BK=32, 4 waves, 16x16x32 bf16 MFMA ----------------
// A: [M][K] row-major bf16 (lda=K elems). B: [N][K] row-major bf16 ("B^T" layout).
__device__ __forceinline__ void gemm_tile(const u16* __restrict__ Abase, int lda,
                                          const u16* __restrict__ Bbase, int ldb,
                                          int kTiles, u16* As, u16* Bs,
                                          f32x4 acc[4][4]) {
  int t = threadIdx.x;
  int w = t >> 6, l = t & 63;
  int wr = w >> 1, wc = w & 1;
  int bo0 = t * 16;
  int r0 = bo0 >> 6, c0 = bo0 & 63;
  int bo1 = 4096 + t * 16;
  int r1 = bo1 >> 6, c1 = bo1 & 63;
  const u16* a0 = Abase + (size_t)r0 * lda + (c0 >> 1);
  const u16* a1 = Abase + (size_t)r1 * lda + (c1 >> 1);
  const u16* b0 = Bbase + (size_t)r0 * ldb + (c0 >> 1);
  const u16* b1 = Bbase + (size_t)r1 * ldb + (c1 >> 1);
  u16* lA0 = As + (bo0 >> 1); u16* lA1 = As + (bo1 >> 1);
  u16* lB0 = Bs + (bo0 >> 1); u16* lB1 = Bs + (bo1 >> 1);

  for (int m = 0; m < 4; m++)
    for (int n = 0; n < 4; n++)
      for (int j = 0; j < 4; j++) acc[m][n][j] = 0.f;

  int arow = wr * 64 + (l & 15);
  int brow = wc * 64 + (l & 15);
  int koff = (l >> 4) * 8;

  for (int kt = 0; kt < kTiles; kt++) {
    __syncthreads();
    stage16(a0 + kt * 32, lA0);
    stage16(a1 + kt * 32, lA1);
    stage16(b0 + kt * 32, lB0);
    stage16(b1 + kt * 32, lB1);
    __syncthreads();
    bf16x8 af[4], bq[4];
    for (int m = 0; m < 4; m++)
      af[m] = *(const bf16x8*)&As[(arow + m * 16) * 32 + koff];
    for (int n = 0; n < 4; n++)
      bq[n] = *(const bf16x8*)&Bs[(brow + n * 16) * 32 + koff];
    for (int m = 0; m < 4; m++)
      for (int n = 0; n < 4; n++)
        acc[m][n] = __builtin_amdgcn_mfma_f32_16x16x32_bf16(af[m], bq[n], acc[m][n], 0, 0, 0);
  }
}

// stage 128x128 f32 acc tile as bf16 into smem (32KB), then fully-coalesced stores
__device__ __forceinline__ void store_tile_bf16(const f32x4 acc[4][4], u16* smem,
                                                u16* dst, int ld) {
  int t = threadIdx.x, w = t >> 6, l = t & 63;
  int wr = w >> 1, wc = w & 1;
  int rb = wr * 64 + ((l >> 4) << 2), cb = wc * 64 + (l & 15);
  __syncthreads();            // all LDS reads of As/Bs complete
  for (int m = 0; m < 4; m++)
    for (int j = 0; j < 4; j++) {
      int row = rb + m * 16 + j;
      for (int n = 0; n < 4; n++)
        smem[row * 128 + cb + n * 16] = f2bf(acc[m][n][j]);
    }
  __syncthreads();
  const uint4* sv = (const uint4*)smem;
  #pragma unroll
  for (int i = 0; i < 8; i++) {
    int off = i * 256 + t;
    int row = off >> 4, cu = (off & 15) << 3;   // 128 u16/row = 16 x uint4
    *(uint4*)(dst + (size_t)row * ld + cu) = sv[off];
  }
}

// ---------------- projection GEMM: q,k row-major; v computed transposed ----------------
__global__ __launch_bounds__(256) void gemm_qkv(
    const u16* __restrict__ xb, const u16* __restrict__ Wt,
    u16* __restrict__ qb, u16* __restrict__ kb, u16* __restrict__ vT) {
  __shared__ __align__(16) u16 smem[16384];   // 32 KB: As|Bs during loop, tile in epilogue
  u16* As = smem; u16* Bs = smem + 4096;
  int z = blockIdx.z;
  f32x4 acc[4][4];
  if (z < 2) {
    int m0 = blockIdx.x * 128, n0 = blockIdx.y * 128;
    const u16* A = xb + (size_t)m0 * F_;
    const u16* Bb = Wt + (size_t)z * D_ * F_ + (size_t)n0 * F_;
    gemm_tile(A, F_, Bb, F_, F_ / 32, As, Bs, acc);
    u16* dst = ((z == 0) ? qb : kb) + (size_t)m0 * D_ + n0;
    store_tile_bf16(acc, smem, dst, D_);
  } else {
    // v^T[d][s] = sum_f WvT[d][f] * x[s][f]
    int d0 = blockIdx.y * 128, s0g = blockIdx.x * 128;
    const u16* A = Wt + 2ULL * D_ * F_ + (size_t)d0 * F_;
    const u16* Bb = xb + (size_t)s0g * F_;
    gemm_tile(A, F_, Bb, F_, F_ / 32, As, Bs, acc);
    int b = s0g >> 11, s0 = s0g & 2047;
    u16* dst = vT + (size_t)b * D_ * S_ + (size_t)d0 * S_ + s0;
    store_tile_bf16(acc, smem, dst, S_);
  }
}

// ---------------- scores: P = exp(qk/32 + r_sm - 16) (masked), partial row sums ----------------
__global__ __launch_bounds__(256) void attn_scores(
    const u16* __restrict__ qb, const u16* __restrict__ kb,
    const float* __restrict__ r_mat, const float* __restrict__ pm,
    const float* __restrict__ rs_r, u16* __restrict__ P,
    float* __restrict__ rowsum) {
  int mt = blockIdx.x, nt = blockIdx.y, b = blockIdx.z;
  if (nt > mt) return;                    // fully above causal diagonal
  __shared__ __align__(16) u16 smem[16384];
  u16* As = smem; u16* Bs = smem + 4096;
  int m0 = mt * 128, n0 = nt * 128;
  const u16* A = qb + ((size_t)b * S_ + m0) * D_;
  const u16* Bb = kb + ((size_t)b * S_ + n0) * D_;
  f32x4 acc[4][4];
  gemm_tile(A, D_, Bb, D_, D_ / 32, As, Bs, acc);
  int t = threadIdx.x, w = t >> 6, l = t & 63;
  int wr = w >> 1, wc = w & 1;
  const float* rb = r_mat + (size_t)b * S_ * S_;
  const float* pmp = pm + (size_t)b * S_;
  // transform acc in place to P values; accumulate row sums
  for (int m = 0; m < 4; m++)
    for (int j = 0; j < 4; j++) {
      int s = m0 + wr * 64 + m * 16 + ((l >> 4) << 2) + j;
      float invr = 1.f / rs_r[b * S_ + s];
      const float* rrow = rb + (size_t)s * S_;
      float rsum = 0.f;
      for (int n = 0; n < 4; n++) {
        int tc = n0 + wc * 64 + n * 16 + (l & 15);
        bool keep = (tc <= s) && (pmp[tc] != 0.f);
        float e = 0.f;
        if (keep) {
          float lg = acc[m][n][j] * (1.f / 32.f) + __expf(rrow[tc] - 16.f) * invr;
          e = bf2f(f2bf(__expf(lg - 16.f)));
        }
        acc[m][n][j] = e;
        rsum += e;
      }
      for (int off = 1; off < 16; off <<= 1) rsum += __shfl_xor(rsum, off);
      if ((l & 15) == 0) atomicAdd(&rowsum[b * S_ + s], rsum);
    }
  u16* dst = P + (size_t)b * S_ * S_ + (size_t)m0 * S_ + n0;
  store_tile_bf16(acc, smem, dst, S_);
}

// ---------------- PV: out = (P @ V) / rowsum ----------------
__global__ __launch_bounds__(256) void attn_pv(
    const u16* __restrict__ P, const u16* __restrict__ vT,
    const float* __restrict__ rowsum, float* __restrict__ out) {
  __shared__ __align__(16) u16 smem[16384];
  u16* As = smem; u16* Bs = smem + 4096;
  int mt = blockIdx.x, dt = blockIdx.y, b = blockIdx.z;
  int m0 = mt * 128, n0 = dt * 128;
  int kmax = m0 + 128;                    // causal: P row s has support t <= s
  const u16* A = P + ((size_t)b * S_ + m0) * S_;
  const u16* Bb = vT + ((size_t)b * D_ + n0) * S_;
  f32x4 acc[4][4];
  gemm_tile(A, S_, Bb, S_, kmax / 32, As, Bs, acc);
  int t = threadIdx.x, w = t >> 6, l = t & 63;
  int wr = w >> 1, wc = w & 1;
  int cb = wc * 64 + (l & 15);
  float* fs = (float*)smem;               // 32KB = 64 rows x 128 f32
  #pragma unroll
  for (int h = 0; h < 2; h++) {
    __syncthreads();
    if (wr == h) {
      for (int m = 0; m < 4; m++)
        for (int j = 0; j < 4; j++) {
          int row = ((l >> 4) << 2) + m * 16 + j;     // 0..63 within half
          float inv = 1.f / rowsum[b * S_ + m0 + h * 64 + row];
          for (int n = 0; n < 4; n++)
            fs[row * 128 + cb + n * 16] = acc[m][n][j] * inv;
        }
    }
    __syncthreads();
    const float4* sv = (const float4*)fs;
    #pragma unroll
    for (int i = 0; i < 8; i++) {
      int off = i * 256 + t;
      int row = off >> 5, c4 = (off & 31) << 2;       // 128 f32/row = 32 x float4
      *(float4*)(out + ((size_t)b * S_ + m0 + h * 64 + row) * D_ + n0 + c4) = sv[off];
    }
  }
}

// ---------------- launch ----------------
extern "C" void kernel_launch(void* const* d_in, const int* in_sizes, int n_in,
                              void* d_out, int out_size, void* d_ws, size_t ws_size,
                              hipStream_t stream) {
  const float* x     = (const float*)d_in[0];
  const float* r_mat = (const float*)d_in[1];
  const float* pm    = (const float*)d_in[3];
  const float* Wq    = (const float*)d_in[4];
  const float* Wk    = (const float*)d_in[5];
  const float* Wv    = (const float*)d_in[6];
  float* out = (float*)d_out;
  char* ws = (char*)d_ws;

  u16*   qb     = (u16*)(ws + 0);
  u16*   kb     = (u16*)(ws + 33554432ULL);
  u16*   vT     = (u16*)(ws + 67108864ULL);
  float* rs_r   = (float*)(ws + 100663296ULL);
  float* rowsum = (float*)(ws + 100728832ULL);
  u16*   P      = (u16*)(ws + 100794368ULL);   // aliases xb+Wt region (dead by then)
  u16*   xb     = (u16*)(ws + 100794368ULL);
  u16*   Wt     = (u16*)(ws + 134348800ULL);

  cast_x<<<dim3(2048), dim3(256), 0, stream>>>(x, xb, (B_ * S_ * F_) / 4);
  transW<<<dim3(32, 32, 3), dim3(256), 0, stream>>>(Wq, Wk, Wv, Wt);
  r_rowsum<<<dim3(B_ * S_), dim3(256), 0, stream>>>(r_mat, pm, rs_r);
  gemm_qkv<<<dim3(128, 8, 3), dim3(256), 0, stream>>>(xb, Wt, qb, kb, vT);
  hipMemsetAsync(rowsum, 0, B_ * S_ * sizeof(float), stream);
  attn_scores<<<dim3(16, 16, 8), dim3(256), 0, stream>>>(qb, kb, r_mat, pm, rs_r, P, rowsum);
  attn_pv<<<dim3(16, 8, 8), dim3(256), 0, stream>>>(P, vT, rowsum, out);
}

// Round 3
// 432.644 us; speedup vs baseline: 2.4969x; 1.1099x over previous
//
#include <hip/hip_runtime.h>
#include <hip/hip_bf16.h>

#define B_ 8
#define S_ 2048
#define F_ 1024
#define D_ 1024

typedef unsigned short u16;
typedef float f32x4 __attribute__((ext_vector_type(4)));
typedef __bf16 bf16x8 __attribute__((ext_vector_type(8)));
typedef unsigned short u16x8 __attribute__((ext_vector_type(8)));

__device__ __forceinline__ u16 f2bf(float f) {
  union { float f; unsigned u; } v; v.f = f;
  unsigned r = v.u + 0x7fff + ((v.u >> 16) & 1);
  return (u16)(r >> 16);
}
__device__ __forceinline__ float bf2f(u16 b) {
  union { unsigned u; float f; } v; v.u = ((unsigned)b) << 16;
  return v.f;
}

__device__ __forceinline__ void stage16(const u16* g, u16* l) {
  __builtin_amdgcn_global_load_lds(
      (const __attribute__((address_space(1))) void*)g,
      (__attribute__((address_space(3))) void*)l, 16, 0, 0);
}

// ---------------- prep kernels ----------------

__global__ void cast_x(const float* __restrict__ x, u16* __restrict__ xb, int n4) {
  int i = blockIdx.x * blockDim.x + threadIdx.x;
  int stride = gridDim.x * blockDim.x;
  for (; i < n4; i += stride) {
    float4 v = ((const float4*)x)[i];
    ushort4 o;
    o.x = f2bf(v.x); o.y = f2bf(v.y); o.z = f2bf(v.z); o.w = f2bf(v.w);
    ((ushort4*)xb)[i] = o;
  }
}

__global__ void transW(const float* __restrict__ Wq, const float* __restrict__ Wk,
                       const float* __restrict__ Wv, u16* __restrict__ Wt) {
  __shared__ float tile[32][33];
  int z = blockIdx.z;
  const float* W = (z == 0) ? Wq : ((z == 1) ? Wk : Wv);
  int f0 = blockIdx.y * 32, d0 = blockIdx.x * 32;
  int tx = threadIdx.x & 31, ty = threadIdx.x >> 5;
  for (int i = 0; i < 4; i++)
    tile[ty + i * 8][tx] = W[(size_t)(f0 + ty + i * 8) * D_ + d0 + tx];
  __syncthreads();
  u16* o = Wt + (size_t)z * D_ * F_;
  for (int i = 0; i < 4; i++)
    o[(size_t)(d0 + ty + i * 8) * F_ + f0 + tx] = f2bf(tile[tx][ty + i * 8]);
}

// row sums of exp(r - 16) over kept positions (causal: t<=s; pad from memory)
__global__ __launch_bounds__(256) void r_rowsum(const float* __restrict__ r,
                                                const float* __restrict__ pm,
                                                float* __restrict__ rs) {
  int row = blockIdx.x;            // b*S + s
  int b = row >> 11, s = row & 2047;
  const float4* rp = (const float4*)(r + (size_t)row * S_);
  const float4* pp = (const float4*)(pm + (size_t)b * S_);
  int nv = (s >> 2) + 1;
  float acc = 0.f;
  for (int i = threadIdx.x; i < nv; i += 256) {
    float4 rv = rp[i];
    float4 pv = pp[i];
    int t0 = i << 2;
    #pragma unroll
    for (int j = 0; j < 4; j++) {
      int t = t0 + j;
      if (t <= s && (&pv.x)[j] != 0.f) acc += __expf((&rv.x)[j] - 16.f);
    }
  }
  for (int off = 1; off < 64; off <<= 1) acc += __shfl_xor(acc, off);
  __shared__ float wsum[4];
  int lane = threadIdx.x & 63, w = threadIdx.x >> 6;
  if (lane == 0) wsum[w] = acc;
  __syncthreads();
  if (threadIdx.x == 0) rs[row] = wsum[0] + wsum[1] + wsum[2] + wsum[3];
}

// Er = keep ? exp(exp(r-16)/rowsum_r) : 0, bf16, written into the P buffer.
// Masking is folded here so the scores epilogue needs no mask logic.
__global__ __launch_bounds__(256) void er_pass(const float* __restrict__ r,
                                               const float* __restrict__ pm,
                                               const float* __restrict__ rs_r,
                                               u16* __restrict__ Er) {
  int row = blockIdx.x * 2 + (threadIdx.x >> 7);   // b*S + s
  int b = row >> 11, s = row & 2047;
  int rowlim = ((s >> 7) + 1) << 7;                // tile-rounded causal extent
  float invr = 1.f / rs_r[row];
  const float4* rp = (const float4*)(r + (size_t)row * S_);
  const float4* pp = (const float4*)(pm + (size_t)b * S_);
  ushort4* erow = (ushort4*)(Er + (size_t)row * S_);
  int tc = threadIdx.x & 127;
  for (int c4 = tc; c4 * 4 < rowlim; c4 += 128) {
    float4 rv = rp[c4];
    float4 pv = pp[c4];
    int t0 = c4 * 4;
    ushort4 o;
    #pragma unroll
    for (int j = 0; j < 4; j++) {
      bool keep = (t0 + j <= s) && ((&pv.x)[j] != 0.f);
      float e = keep ? __expf(__expf((&rv.x)[j] - 16.f) * invr) : 0.f;
      (&o.x)[j] = f2bf(e);
    }
    erow[c4] = o;
  }
}

// ---------------- GEMM core: 128x128 tile, BK=32, 4 waves, 16x16x32 bf16 MFMA ----------------
__device__ __forceinline__ void gemm_tile(const u16* __restrict__ Abase, int lda,
                                          const u16* __restrict__ Bbase, int ldb,
                                          int kTiles, u16* As, u16* Bs,
                                          f32x4 acc[4][4]) {
  int t = threadIdx.x;
  int w = t >> 6, l = t & 63;
  int wr = w >> 1, wc = w & 1;
  int bo0 = t * 16;
  int r0 = bo0 >> 6, c0 = bo0 & 63;
  int bo1 = 4096 + t * 16;
  int r1 = bo1 >> 6, c1 = bo1 & 63;
  const u16* a0 = Abase + (size_t)r0 * lda + (c0 >> 1);
  const u16* a1 = Abase + (size_t)r1 * lda + (c1 >> 1);
  const u16* b0 = Bbase + (size_t)r0 * ldb + (c0 >> 1);
  const u16* b1 = Bbase + (size_t)r1 * ldb + (c1 >> 1);
  u16* lA0 = As + (bo0 >> 1); u16* lA1 = As + (bo1 >> 1);
  u16* lB0 = Bs + (bo0 >> 1); u16* lB1 = Bs + (bo1 >> 1);

  for (int m = 0; m < 4; m++)
    for (int n = 0; n < 4; n++)
      for (int j = 0; j < 4; j++) acc[m][n][j] = 0.f;

  int arow = wr * 64 + (l & 15);
  int brow = wc * 64 + (l & 15);
  int koff = (l >> 4) * 8;

  for (int kt = 0; kt < kTiles; kt++) {
    __syncthreads();
    stage16(a0 + kt * 32, lA0);
    stage16(a1 + kt * 32, lA1);
    stage16(b0 + kt * 32, lB0);
    stage16(b1 + kt * 32, lB1);
    __syncthreads();
    bf16x8 af[4], bq[4];
    for (int m = 0; m < 4; m++)
      af[m] = *(const bf16x8*)&As[(arow + m * 16) * 32 + koff];
    for (int n = 0; n < 4; n++)
      bq[n] = *(const bf16x8*)&Bs[(brow + n * 16) * 32 + koff];
    for (int m = 0; m < 4; m++)
      for (int n = 0; n < 4; n++)
        acc[m][n] = __builtin_amdgcn_mfma_f32_16x16x32_bf16(af[m], bq[n], acc[m][n], 0, 0, 0);
  }
}

// stage 128x128 acc as bf16 through LDS (two 64-row halves, stride 136), coalesced stores
__device__ __forceinline__ void store_tile_bf16(const f32x4 acc[4][4], u16* smem,
                                                u16* dst, int ld) {
  int t = threadIdx.x, w = t >> 6, l = t & 63;
  int wr = w >> 1, wc = w & 1;
  #pragma unroll
  for (int h = 0; h < 2; h++) {
    __syncthreads();
    if (wr == h) {
      for (int m = 0; m < 4; m++)
        for (int j = 0; j < 4; j++) {
          int row = m * 16 + ((l >> 4) << 2) + j;   // 0..63
          for (int n = 0; n < 4; n++)
            smem[row * 136 + wc * 64 + n * 16 + (l & 15)] = f2bf(acc[m][n][j]);
        }
    }
    __syncthreads();
    #pragma unroll
    for (int i = 0; i < 4; i++) {
      int off = i * 256 + t;
      int row = off >> 4, cu = (off & 15) << 3;
      *(uint4*)(dst + (size_t)(h * 64 + row) * ld + cu) =
          *(const uint4*)(smem + row * 136 + cu);
    }
  }
}

// ---------------- projection GEMM: q,k row-major; v computed transposed ----------------
__global__ __launch_bounds__(256) void gemm_qkv(
    const u16* __restrict__ xb, const u16* __restrict__ Wt,
    u16* __restrict__ qb, u16* __restrict__ kb, u16* __restrict__ vT) {
  __shared__ __align__(16) u16 smem[8704];    // 17 KB
  u16* As = smem; u16* Bs = smem + 4096;
  int z = blockIdx.z;
  f32x4 acc[4][4];
  if (z < 2) {
    int m0 = blockIdx.x * 128, n0 = blockIdx.y * 128;
    const u16* A = xb + (size_t)m0 * F_;
    const u16* Bb = Wt + (size_t)z * D_ * F_ + (size_t)n0 * F_;
    gemm_tile(A, F_, Bb, F_, F_ / 32, As, Bs, acc);
    u16* dst = ((z == 0) ? qb : kb) + (size_t)m0 * D_ + n0;
    store_tile_bf16(acc, smem, dst, D_);
  } else {
    // v^T[d][s] = sum_f WvT[d][f] * x[s][f]
    int d0 = blockIdx.y * 128, s0g = blockIdx.x * 128;
    const u16* A = Wt + 2ULL * D_ * F_ + (size_t)d0 * F_;
    const u16* Bb = xb + (size_t)s0g * F_;
    gemm_tile(A, F_, Bb, F_, F_ / 32, As, Bs, acc);
    int b = s0g >> 11, s0 = s0g & 2047;
    u16* dst = vT + (size_t)b * D_ * S_ + (size_t)d0 * S_ + s0;
    store_tile_bf16(acc, smem, dst, S_);
  }
}

// ---------------- scores: P = exp(qk/32 - 16) * Er (Er pre-masked), row sums ----------------
__global__ __launch_bounds__(256) void attn_scores(
    const u16* __restrict__ qb, const u16* __restrict__ kb,
    u16* __restrict__ P, float* __restrict__ rowsum) {
  int mt = blockIdx.x, nt = blockIdx.y, b = blockIdx.z;
  if (nt > mt) return;
  __shared__ __align__(16) u16 smem[8704];
  u16* As = smem; u16* Bs = smem + 4096;
  int m0 = mt * 128, n0 = nt * 128;
  const u16* A = qb + ((size_t)b * S_ + m0) * D_;
  const u16* Bb = kb + ((size_t)b * S_ + n0) * D_;
  f32x4 acc[4][4];
  gemm_tile(A, D_, Bb, D_, D_ / 32, As, Bs, acc);
  int t = threadIdx.x, w = t >> 6, l = t & 63;
  int wr = w >> 1, wc = w & 1;
  float* fs = (float*)smem;
  u16* Pb = P + (size_t)b * S_ * S_ + (size_t)m0 * S_ + n0;
  #pragma unroll
  for (int qtr = 0; qtr < 4; qtr++) {
    __syncthreads();
    if (wr == (qtr >> 1)) {
      int mb = (qtr & 1) * 2;
      #pragma unroll
      for (int mm = 0; mm < 2; mm++) {
        int m = mb + mm;
        for (int j = 0; j < 4; j++) {
          int rq = mm * 16 + ((l >> 4) << 2) + j;   // 0..31
          for (int n = 0; n < 4; n++)
            fs[rq * 132 + wc * 64 + n * 16 + (l & 15)] = acc[m][n][j];
        }
      }
    }
    __syncthreads();
    int rq = t >> 3, c0 = (t & 7) * 16;
    int srow = m0 + qtr * 32 + rq;
    u16* prow = Pb + (size_t)(qtr * 32 + rq) * S_ + c0;
    u16x8 er0 = *(const u16x8*)prow;
    u16x8 er1 = *(const u16x8*)(prow + 8);
    const float* frow = fs + rq * 132 + c0;
    f32x4 fv[4];
    #pragma unroll
    for (int kk = 0; kk < 4; kk++) fv[kk] = *(const f32x4*)(frow + 4 * kk);
    float rsum = 0.f;
    u16x8 o0, o1;
    #pragma unroll
    for (int k = 0; k < 8; k++) {
      float e = __expf(fmaf(fv[k >> 2][k & 3], 0.03125f, -16.f)) * bf2f(er0[k]);
      u16 pb = f2bf(e); o0[k] = pb; rsum += bf2f(pb);
    }
    #pragma unroll
    for (int k = 0; k < 8; k++) {
      float e = __expf(fmaf(fv[2 + (k >> 2)][k & 3], 0.03125f, -16.f)) * bf2f(er1[k]);
      u16 pb = f2bf(e); o1[k] = pb; rsum += bf2f(pb);
    }
    *(u16x8*)prow = o0;
    *(u16x8*)(prow + 8) = o1;
    for (int off = 1; off < 8; off <<= 1) rsum += __shfl_xor(rsum, off);
    if ((t & 7) == 0) atomicAdd(&rowsum[b * S_ + srow], rsum);
  }
}

// ---------------- PV: out = (P @ V) / rowsum ----------------
__global__ __launch_bounds__(256) void attn_pv(
    const u16* __restrict__ P, const u16* __restrict__ vT,
    const float* __restrict__ rowsum, float* __restrict__ out) {
  __shared__ __align__(16) u16 smem[8704];
  u16* As = smem; u16* Bs = smem + 4096;
  int mt = blockIdx.x, dt = blockIdx.y, b = blockIdx.z;
  int m0 = mt * 128, n0 = dt * 128;
  int kmax = m0 + 128;                    // causal support
  const u16* A = P + ((size_t)b * S_ + m0) * S_;
  const u16* Bb = vT + ((size_t)b * D_ + n0) * S_;
  f32x4 acc[4][4];
  gemm_tile(A, S_, Bb, S_, kmax / 32, As, Bs, acc);
  int t = threadIdx.x, w = t >> 6, l = t & 63;
  int wr = w >> 1, wc = w & 1;
  float* fs = (float*)smem;
  #pragma unroll
  for (int qtr = 0; qtr < 4; qtr++) {
    __syncthreads();
    if (wr == (qtr >> 1)) {
      int mb = (qtr & 1) * 2;
      #pragma unroll
      for (int mm = 0; mm < 2; mm++) {
        int m = mb + mm;
        for (int j = 0; j < 4; j++) {
          int rq = mm * 16 + ((l >> 4) << 2) + j;
          float inv = 1.f / rowsum[b * S_ + m0 + qtr * 32 + rq];
          for (int n = 0; n < 4; n++)
            fs[rq * 132 + wc * 64 + n * 16 + (l & 15)] = acc[m][n][j] * inv;
        }
      }
    }
    __syncthreads();
    #pragma unroll
    for (int i = 0; i < 4; i++) {
      int off = i * 256 + t;                        // float4 index
      int row = off >> 5, c4 = (off & 31) << 2;
      *(float4*)(out + ((size_t)b * S_ + m0 + qtr * 32 + row) * D_ + n0 + c4) =
          *(const float4*)(fs + row * 132 + c4);
    }
  }
}

// ---------------- launch ----------------
extern "C" void kernel_launch(void* const* d_in, const int* in_sizes, int n_in,
                              void* d_out, int out_size, void* d_ws, size_t ws_size,
                              hipStream_t stream) {
  const float* x     = (const float*)d_in[0];
  const float* r_mat = (const float*)d_in[1];
  const float* pm    = (const float*)d_in[3];
  const float* Wq    = (const float*)d_in[4];
  const float* Wk    = (const float*)d_in[5];
  const float* Wv    = (const float*)d_in[6];
  float* out = (float*)d_out;
  char* ws = (char*)d_ws;

  u16*   qb     = (u16*)(ws + 0);
  u16*   kb     = (u16*)(ws + 33554432ULL);
  u16*   vT     = (u16*)(ws + 67108864ULL);
  float* rs_r   = (float*)(ws + 100663296ULL);
  float* rowsum = (float*)(ws + 100728832ULL);
  u16*   P      = (u16*)(ws + 100794368ULL);   // holds Er then P; aliases xb (dead by then)
  u16*   xb     = (u16*)(ws + 100794368ULL);
  u16*   Wt     = (u16*)(ws + 134348800ULL);

  cast_x<<<dim3(2048), dim3(256), 0, stream>>>(x, xb, (B_ * S_ * F_) / 4);
  transW<<<dim3(32, 32, 3), dim3(256), 0, stream>>>(Wq, Wk, Wv, Wt);
  r_rowsum<<<dim3(B_ * S_), dim3(256), 0, stream>>>(r_mat, pm, rs_r);
  gemm_qkv<<<dim3(128, 8, 3), dim3(256), 0, stream>>>(xb, Wt, qb, kb, vT);
  hipMemsetAsync(rowsum, 0, B_ * S_ * sizeof(float), stream);
  // er_pass writes the P buffer (aliases xb) -> must run after gemm_qkv
  er_pass<<<dim3(B_ * S_ / 2), dim3(256), 0, stream>>>(r_mat, pm, rs_r, P);
  attn_scores<<<dim3(16, 16, 8), dim3(256), 0, stream>>>(qb, kb, P, rowsum);
  attn_pv<<<dim3(16, 8, 8), dim3(256), 0, stream>>>(P, vT, rowsum, out);
}

// Round 4
// 315.223 us; speedup vs baseline: 3.4271x; 1.3725x over previous
//
#include <hip/hip_runtime.h>
#include <hip/hip_bf16.h>

#define B_ 8
#define S_ 2048
#define F_ 1024
#define D_ 1024

typedef unsigned short u16;
typedef float f32x4 __attribute__((ext_vector_type(4)));
typedef __bf16 bf16x8 __attribute__((ext_vector_type(8)));
typedef unsigned short u16x8 __attribute__((ext_vector_type(8)));

__device__ __forceinline__ u16 f2bf(float f) {
  union { float f; unsigned u; } v; v.f = f;
  unsigned r = v.u + 0x7fff + ((v.u >> 16) & 1);
  return (u16)(r >> 16);
}
__device__ __forceinline__ float bf2f(u16 b) {
  union { unsigned u; float f; } v; v.u = ((unsigned)b) << 16;
  return v.f;
}

__device__ __forceinline__ void stage16(const u16* g, u16* l) {
  __builtin_amdgcn_global_load_lds(
      (const __attribute__((address_space(1))) void*)g,
      (__attribute__((address_space(3))) void*)l, 16, 0, 0);
}

// ---------------- prep kernels ----------------

__global__ void cast_x(const float* __restrict__ x, u16* __restrict__ xb, int n4) {
  int i = blockIdx.x * blockDim.x + threadIdx.x;
  int stride = gridDim.x * blockDim.x;
  for (; i < n4; i += stride) {
    float4 v = ((const float4*)x)[i];
    ushort4 o;
    o.x = f2bf(v.x); o.y = f2bf(v.y); o.z = f2bf(v.z); o.w = f2bf(v.w);
    ((ushort4*)xb)[i] = o;
  }
}

__global__ void transW(const float* __restrict__ Wq, const float* __restrict__ Wk,
                       const float* __restrict__ Wv, u16* __restrict__ Wt) {
  __shared__ float tile[32][33];
  int z = blockIdx.z;
  const float* W = (z == 0) ? Wq : ((z == 1) ? Wk : Wv);
  int f0 = blockIdx.y * 32, d0 = blockIdx.x * 32;
  int tx = threadIdx.x & 31, ty = threadIdx.x >> 5;
  for (int i = 0; i < 4; i++)
    tile[ty + i * 8][tx] = W[(size_t)(f0 + ty + i * 8) * D_ + d0 + tx];
  __syncthreads();
  u16* o = Wt + (size_t)z * D_ * F_;
  for (int i = 0; i < 4; i++)
    o[(size_t)(d0 + ty + i * 8) * F_ + f0 + tx] = f2bf(tile[tx][ty + i * 8]);
}

__global__ __launch_bounds__(256) void r_rowsum(const float* __restrict__ r,
                                                const float* __restrict__ pm,
                                                float* __restrict__ rs) {
  int row = blockIdx.x;            // b*S + s
  int b = row >> 11, s = row & 2047;
  const float4* rp = (const float4*)(r + (size_t)row * S_);
  const float4* pp = (const float4*)(pm + (size_t)b * S_);
  int nv = (s >> 2) + 1;
  float acc = 0.f;
  for (int i = threadIdx.x; i < nv; i += 256) {
    float4 rv = rp[i];
    float4 pv = pp[i];
    int t0 = i << 2;
    #pragma unroll
    for (int j = 0; j < 4; j++) {
      int t = t0 + j;
      if (t <= s && (&pv.x)[j] != 0.f) acc += __expf((&rv.x)[j] - 16.f);
    }
  }
  for (int off = 1; off < 64; off <<= 1) acc += __shfl_xor(acc, off);
  __shared__ float wsum[4];
  int lane = threadIdx.x & 63, w = threadIdx.x >> 6;
  if (lane == 0) wsum[w] = acc;
  __syncthreads();
  if (threadIdx.x == 0) rs[row] = wsum[0] + wsum[1] + wsum[2] + wsum[3];
}

// Er = keep ? exp(exp(r-16)/rowsum_r) : 0, bf16, into the P buffer.
// Zero-extent rounded to 256 (the score tile width) so PV never reads garbage.
__global__ __launch_bounds__(256) void er_pass(const float* __restrict__ r,
                                               const float* __restrict__ pm,
                                               const float* __restrict__ rs_r,
                                               u16* __restrict__ Er) {
  int row = blockIdx.x * 2 + (threadIdx.x >> 7);   // b*S + s
  int b = row >> 11, s = row & 2047;
  int rowlim = ((s >> 8) + 1) << 8;                // 256-tile-rounded causal extent
  float invr = 1.f / rs_r[row];
  const float4* rp = (const float4*)(r + (size_t)row * S_);
  const float4* pp = (const float4*)(pm + (size_t)b * S_);
  ushort4* erow = (ushort4*)(Er + (size_t)row * S_);
  int tc = threadIdx.x & 127;
  for (int c4 = tc; c4 * 4 < rowlim; c4 += 128) {
    float4 rv = rp[c4];
    float4 pv = pp[c4];
    int t0 = c4 * 4;
    ushort4 o;
    #pragma unroll
    for (int j = 0; j < 4; j++) {
      bool keep = (t0 + j <= s) && ((&pv.x)[j] != 0.f);
      float e = keep ? __expf(__expf((&rv.x)[j] - 16.f) * invr) : 0.f;
      (&o.x)[j] = f2bf(e);
    }
    erow[c4] = o;
  }
}

// =============== 256x256 / BK=64 / 8-wave pipelined GEMM engine ===============
// A: [M][K] row-major bf16, B: [N][K] row-major bf16 (B^T layout).
// LDS: 128 KB = 2 buffers x (A 256x64 + B 256x64) bf16, linear layout,
// XOR-swizzled reads (chunk ^= row&7) with inverse-swizzled global staging src.

// stage one "half" (128 rows) of a 256x64 tile; this wave's 16 rows (2 issues).
// A halves are interleaved per-warp-row: half h covers rows (wr*128+h*64 .. +64)
// across both wr regions; B halves are contiguous 128-row blocks.
__device__ __forceinline__ void stageA(const u16* __restrict__ src, int ld, int h,
                                       u16* ldsA, int w, int l) {
  int base = ((w >> 2) * 128) + h * 64 + ((w & 3) * 16);
  int r = l >> 3, ch = (l & 7) ^ (l >> 3);
  #pragma unroll
  for (int i = 0; i < 2; i++) {
    int row = base + i * 8;
    stage16(src + (size_t)(row + r) * ld + ch * 8, ldsA + row * 64);
  }
}
__device__ __forceinline__ void stageB(const u16* __restrict__ src, int ld, int h,
                                       u16* ldsB, int w, int l) {
  int base = h * 128 + w * 16;
  int r = l >> 3, ch = (l & 7) ^ (l >> 3);
  #pragma unroll
  for (int i = 0; i < 2; i++) {
    int row = base + i * 8;
    stage16(src + (size_t)(row + r) * ld + ch * 8, ldsB + row * 64);
  }
}

__device__ __forceinline__ bf16x8 readfrag(const u16* lds, int row, int ks, int hi) {
  int c = ((ks << 6) + (hi << 4)) ^ ((row & 7) << 4);   // byte offset in row
  return *(const bf16x8*)((const char*)lds + row * 128 + c);
}

#define MFMA_QUAD(MB, KS)                                                        \
  __builtin_amdgcn_s_setprio(1);                                                 \
  _Pragma("unroll")                                                              \
  for (int m = 0; m < 4; m++)                                                    \
    _Pragma("unroll")                                                            \
    for (int n = 0; n < 4; n++)                                                  \
      acc[(MB) + m][n] = __builtin_amdgcn_mfma_f32_16x16x32_bf16(                \
          af[m], bfr[(KS)*4 + n], acc[(MB) + m][n], 0, 0, 0);                    \
  __builtin_amdgcn_s_setprio(0);

__device__ __forceinline__ void gemm256(const u16* __restrict__ A, int lda,
                                        const u16* __restrict__ B, int ldb,
                                        int nT, u16* lds, f32x4 acc[8][4]) {
  const int t = threadIdx.x, w = t >> 6, l = t & 63;
  const int wr = w >> 2, wc = w & 3;
  u16* A0 = lds;           u16* B0 = lds + 16384;
  u16* A1 = lds + 32768;   u16* B1 = lds + 49152;

  #pragma unroll
  for (int m = 0; m < 8; m++)
    #pragma unroll
    for (int n = 0; n < 4; n++)
      #pragma unroll
      for (int j = 0; j < 4; j++) acc[m][n][j] = 0.f;

  // prologue: B0(0),B1(0),Aa(0),Ab(0),Aa(1)
  stageB(B, ldb, 0, B0, w, l);
  stageB(B, ldb, 1, B0, w, l);
  stageA(A, lda, 0, A0, w, l);
  stageA(A, lda, 1, A0, w, l);
  if (nT > 1) stageA(A + 64, lda, 0, A1, w, l);
  asm volatile("s_waitcnt vmcnt(4)" ::: "memory");
  __builtin_amdgcn_sched_barrier(0);
  __builtin_amdgcn_s_barrier();

  for (int kt = 0; kt < nT; kt++) {
    u16* cA = (kt & 1) ? A1 : A0;
    u16* cB = (kt & 1) ? B1 : B0;
    u16* nA = (kt & 1) ? A0 : A1;
    u16* nB = (kt & 1) ? B0 : B1;
    const u16* An1 = A + (size_t)(kt + 1) * 64;
    const u16* Bn1 = B + (size_t)(kt + 1) * 64;
    const u16* An2 = A + (size_t)(kt + 2) * 64;
    const bool has1 = (kt + 1 < nT), has2 = (kt + 2 < nT);
    const int arow = wr * 128 + (l & 15), brow = wc * 64 + (l & 15), hi = l >> 4;
    bf16x8 af[4], bfr[8];

    // phase 1: A(alpha,ks0) + B(ks0); issue B-half0(t+1)
    #pragma unroll
    for (int m = 0; m < 4; m++) af[m] = readfrag(cA, arow + m * 16, 0, hi);
    #pragma unroll
    for (int n = 0; n < 4; n++) bfr[n] = readfrag(cB, brow + n * 16, 0, hi);
    if (has1) stageB(Bn1, ldb, 0, nB, w, l);
    __builtin_amdgcn_s_barrier();
    MFMA_QUAD(0, 0)
    __builtin_amdgcn_s_barrier();

    // phase 2: A(alpha,ks1) + B(ks1); issue B-half1(t+1); counted wait
    #pragma unroll
    for (int m = 0; m < 4; m++) af[m] = readfrag(cA, arow + m * 16, 1, hi);
    #pragma unroll
    for (int n = 0; n < 4; n++) bfr[4 + n] = readfrag(cB, brow + n * 16, 1, hi);
    if (has1) {
      stageB(Bn1, ldb, 1, nB, w, l);
      asm volatile("s_waitcnt vmcnt(4)" ::: "memory");
    } else {
      asm volatile("s_waitcnt vmcnt(0)" ::: "memory");
    }
    __builtin_amdgcn_sched_barrier(0);
    __builtin_amdgcn_s_barrier();
    MFMA_QUAD(0, 1)
    __builtin_amdgcn_s_barrier();

    // phase 3: A(beta,ks0), reuse B ks0; issue A-alpha(t+2) into freed region
    #pragma unroll
    for (int m = 0; m < 4; m++) af[m] = readfrag(cA, arow + 64 + m * 16, 0, hi);
    if (has2) stageA(An2, lda, 0, cA, w, l);
    __builtin_amdgcn_s_barrier();
    MFMA_QUAD(4, 0)
    __builtin_amdgcn_s_barrier();

    // phase 4: A(beta,ks1), reuse B ks1; issue A-beta(t+1); counted wait
    #pragma unroll
    for (int m = 0; m < 4; m++) af[m] = readfrag(cA, arow + 64 + m * 16, 1, hi);
    if (has1) stageA(An1, lda, 1, nA, w, l);
    if (has1 && has2)  { asm volatile("s_waitcnt vmcnt(4)" ::: "memory"); }
    else if (has1)     { asm volatile("s_waitcnt vmcnt(2)" ::: "memory"); }
    __builtin_amdgcn_sched_barrier(0);
    __builtin_amdgcn_s_barrier();
    MFMA_QUAD(4, 1)
    __builtin_amdgcn_s_barrier();
  }
}

// stage 256x256 f32 acc as bf16 through LDS in 64-row quarters; coalesced stores
__device__ __forceinline__ void store256_bf16(f32x4 acc[8][4], u16* smem,
                                              u16* dst, int ld) {
  int t = threadIdx.x, w = t >> 6, l = t & 63;
  int wr = w >> 2, wc = w & 3;
  #pragma unroll
  for (int q = 0; q < 4; q++) {
    __syncthreads();
    if (wr == (q >> 1)) {
      int mb = (q & 1) * 4;
      #pragma unroll
      for (int mm = 0; mm < 4; mm++)
        #pragma unroll
        for (int j = 0; j < 4; j++) {
          int row = mm * 16 + (l >> 4) * 4 + j;
          #pragma unroll
          for (int n = 0; n < 4; n++)
            smem[row * 264 + wc * 64 + n * 16 + (l & 15)] = f2bf(acc[mb + mm][n][j]);
        }
    }
    __syncthreads();
    #pragma unroll
    for (int i = 0; i < 4; i++) {
      int idx = i * 512 + t;            // 2048 u16x8 chunks = 64 rows x 32
      int row = idx >> 5, ch = idx & 31;
      *(u16x8*)(dst + (size_t)(q * 64 + row) * ld + ch * 8) =
          *(const u16x8*)(smem + row * 264 + ch * 8);
    }
  }
}

// ---------------- projection GEMM: q,k row-major; v computed transposed ----------------
__global__ __launch_bounds__(512, 2) void gemm_qkv(
    const u16* __restrict__ xb, const u16* __restrict__ Wt,
    u16* __restrict__ qb, u16* __restrict__ kb, u16* __restrict__ vT) {
  __shared__ __align__(16) u16 lds[65536];   // 128 KB
  int z = blockIdx.z;
  f32x4 acc[8][4];
  if (z < 2) {
    int m0 = blockIdx.x * 256, n0 = blockIdx.y * 256;
    gemm256(xb + (size_t)m0 * F_, F_,
            Wt + (size_t)z * D_ * F_ + (size_t)n0 * F_, F_, F_ / 64, lds, acc);
    store256_bf16(acc, lds, ((z == 0) ? qb : kb) + (size_t)m0 * D_ + n0, D_);
  } else {
    // v^T[d][s] = sum_f WvT[d][f] * x[s][f]
    int d0 = blockIdx.y * 256, s0g = blockIdx.x * 256;
    gemm256(Wt + 2ULL * D_ * F_ + (size_t)d0 * F_, F_,
            xb + (size_t)s0g * F_, F_, F_ / 64, lds, acc);
    int b = s0g >> 11, s0 = s0g & 2047;
    store256_bf16(acc, lds, vT + (size_t)b * D_ * S_ + (size_t)d0 * S_ + s0, S_);
  }
}

// ---------------- scores: P = exp(qk/32 - 16) * Er (Er pre-masked), row sums ----------------
__global__ __launch_bounds__(512, 2) void attn_scores(
    const u16* __restrict__ qb, const u16* __restrict__ kb,
    u16* __restrict__ P, float* __restrict__ rowsum) {
  int mt = blockIdx.x, nt = blockIdx.y, b = blockIdx.z;
  if (nt > mt) return;
  __shared__ __align__(16) u16 lds[65536];
  int m0 = mt * 256, n0 = nt * 256;
  f32x4 acc[8][4];
  gemm256(qb + ((size_t)b * S_ + m0) * D_, D_,
          kb + ((size_t)b * S_ + n0) * D_, D_, D_ / 64, lds, acc);
  int t = threadIdx.x, w = t >> 6, l = t & 63;
  int wr = w >> 2, wc = w & 3;
  float* fs = (float*)lds;                  // 64 x 260 f32 staging
  #pragma unroll
  for (int q = 0; q < 4; q++) {
    __syncthreads();
    if (wr == (q >> 1)) {
      int mb = (q & 1) * 4;
      #pragma unroll
      for (int mm = 0; mm < 4; mm++)
        #pragma unroll
        for (int j = 0; j < 4; j++) {
          int row = mm * 16 + (l >> 4) * 4 + j;
          #pragma unroll
          for (int n = 0; n < 4; n++)
            fs[row * 260 + wc * 64 + n * 16 + (l & 15)] = acc[mb + mm][n][j];
        }
    }
    __syncthreads();
    int row = t >> 3, cg = t & 7;
    int srow = m0 + q * 64 + row;
    u16* prow = P + (size_t)b * S_ * S_ + (size_t)srow * S_ + n0 + cg * 32;
    const float* fsc = fs + row * 260 + cg * 32;
    float rsum = 0.f;
    #pragma unroll
    for (int cc = 0; cc < 4; cc++) {
      int ch = (cg + cc) & 3;               // stagger to dodge LDS bank collisions
      u16x8 er = *(const u16x8*)(prow + ch * 8);
      u16x8 o;
      #pragma unroll
      for (int k = 0; k < 8; k++) {
        float e = __expf(fmaf(fsc[ch * 8 + k], 0.03125f, -16.f)) * bf2f(er[k]);
        u16 pb = f2bf(e); o[k] = pb; rsum += bf2f(pb);
      }
      *(u16x8*)(prow + ch * 8) = o;
    }
    for (int off = 1; off < 8; off <<= 1) rsum += __shfl_xor(rsum, off);
    if ((t & 7) == 0) atomicAdd(&rowsum[b * S_ + srow], rsum);
  }
}

// ---------------- PV: out = (P @ V) / rowsum ----------------
__global__ __launch_bounds__(512, 2) void attn_pv(
    const u16* __restrict__ P, const u16* __restrict__ vT,
    const float* __restrict__ rowsum, float* __restrict__ out) {
  __shared__ __align__(16) u16 lds[65536];
  int mt = blockIdx.x, dt = blockIdx.y, b = blockIdx.z;
  int m0 = mt * 256, n0 = dt * 256;
  int kmax = m0 + 256;                      // causal support, 256-rounded
  f32x4 acc[8][4];
  gemm256(P + ((size_t)b * S_ + m0) * S_, S_,
          vT + ((size_t)b * D_ + n0) * S_, S_, kmax / 64, lds, acc);
  int t = threadIdx.x, w = t >> 6, l = t & 63;
  int wr = w >> 2, wc = w & 3;
  float* fs = (float*)lds;
  #pragma unroll
  for (int q = 0; q < 4; q++) {
    __syncthreads();
    if (wr == (q >> 1)) {
      int mb = (q & 1) * 4;
      #pragma unroll
      for (int mm = 0; mm < 4; mm++)
        #pragma unroll
        for (int j = 0; j < 4; j++) {
          int row = mm * 16 + (l >> 4) * 4 + j;
          float inv = 1.f / rowsum[b * S_ + m0 + q * 64 + row];
          #pragma unroll
          for (int n = 0; n < 4; n++)
            fs[row * 260 + wc * 64 + n * 16 + (l & 15)] = acc[mb + mm][n][j] * inv;
        }
    }
    __syncthreads();
    #pragma unroll
    for (int i = 0; i < 8; i++) {
      int idx = i * 512 + t;                // 4096 float4 = 64 rows x 64
      int row = idx >> 6, c4 = (idx & 63) << 2;
      *(float4*)(out + ((size_t)b * S_ + m0 + q * 64 + row) * D_ + n0 + c4) =
          *(const float4*)(fs + row * 260 + c4);
    }
  }
}

// ---------------- launch ----------------
extern "C" void kernel_launch(void* const* d_in, const int* in_sizes, int n_in,
                              void* d_out, int out_size, void* d_ws, size_t ws_size,
                              hipStream_t stream) {
  const float* x     = (const float*)d_in[0];
  const float* r_mat = (const float*)d_in[1];
  const float* pm    = (const float*)d_in[3];
  const float* Wq    = (const float*)d_in[4];
  const float* Wk    = (const float*)d_in[5];
  const float* Wv    = (const float*)d_in[6];
  float* out = (float*)d_out;
  char* ws = (char*)d_ws;

  u16*   qb     = (u16*)(ws + 0);
  u16*   kb     = (u16*)(ws + 33554432ULL);
  u16*   vT     = (u16*)(ws + 67108864ULL);
  float* rs_r   = (float*)(ws + 100663296ULL);
  float* rowsum = (float*)(ws + 100728832ULL);
  u16*   P      = (u16*)(ws + 100794368ULL);   // holds Er then P; aliases xb (dead by then)
  u16*   xb     = (u16*)(ws + 100794368ULL);
  u16*   Wt     = (u16*)(ws + 134348800ULL);

  cast_x<<<dim3(2048), dim3(256), 0, stream>>>(x, xb, (B_ * S_ * F_) / 4);
  transW<<<dim3(32, 32, 3), dim3(256), 0, stream>>>(Wq, Wk, Wv, Wt);
  r_rowsum<<<dim3(B_ * S_), dim3(256), 0, stream>>>(r_mat, pm, rs_r);
  gemm_qkv<<<dim3(64, 4, 3), dim3(512), 0, stream>>>(xb, Wt, qb, kb, vT);
  hipMemsetAsync(rowsum, 0, B_ * S_ * sizeof(float), stream);
  // er_pass writes the P buffer (aliases xb) -> must run after gemm_qkv
  er_pass<<<dim3(B_ * S_ / 2), dim3(256), 0, stream>>>(r_mat, pm, rs_r, P);
  attn_scores<<<dim3(8, 8, 8), dim3(512), 0, stream>>>(qb, kb, P, rowsum);
  attn_pv<<<dim3(8, 4, 8), dim3(512), 0, stream>>>(P, vT, rowsum, out);
}

// Round 5
// 306.723 us; speedup vs baseline: 3.5220x; 1.0277x over previous
//
#include <hip/hip_runtime.h>
#include <hip/hip_bf16.h>

#define B_ 8
#define S_ 2048
#define F_ 1024
#define D_ 1024

typedef unsigned short u16;
typedef float f32x4 __attribute__((ext_vector_type(4)));
typedef __bf16 bf16x8 __attribute__((ext_vector_type(8)));
typedef unsigned short u16x8 __attribute__((ext_vector_type(8)));

__device__ __forceinline__ u16 f2bf(float f) {
  union { float f; unsigned u; } v; v.f = f;
  unsigned r = v.u + 0x7fff + ((v.u >> 16) & 1);
  return (u16)(r >> 16);
}
__device__ __forceinline__ float bf2f(u16 b) {
  union { unsigned u; float f; } v; v.u = ((unsigned)b) << 16;
  return v.f;
}

__device__ __forceinline__ void stage16(const u16* g, u16* l) {
  __builtin_amdgcn_global_load_lds(
      (const __attribute__((address_space(1))) void*)g,
      (__attribute__((address_space(3))) void*)l, 16, 0, 0);
}

// ---------------- prep kernels ----------------

__global__ void cast_x(const float* __restrict__ x, u16* __restrict__ xb, int n4) {
  int i = blockIdx.x * blockDim.x + threadIdx.x;
  int stride = gridDim.x * blockDim.x;
  for (; i < n4; i += stride) {
    float4 v = ((const float4*)x)[i];
    ushort4 o;
    o.x = f2bf(v.x); o.y = f2bf(v.y); o.z = f2bf(v.z); o.w = f2bf(v.w);
    ((ushort4*)xb)[i] = o;
  }
}

__global__ void transW(const float* __restrict__ Wq, const float* __restrict__ Wk,
                       const float* __restrict__ Wv, u16* __restrict__ Wt) {
  __shared__ float tile[32][33];
  int z = blockIdx.z;
  const float* W = (z == 0) ? Wq : ((z == 1) ? Wk : Wv);
  int f0 = blockIdx.y * 32, d0 = blockIdx.x * 32;
  int tx = threadIdx.x & 31, ty = threadIdx.x >> 5;
  for (int i = 0; i < 4; i++)
    tile[ty + i * 8][tx] = W[(size_t)(f0 + ty + i * 8) * D_ + d0 + tx];
  __syncthreads();
  u16* o = Wt + (size_t)z * D_ * F_;
  for (int i = 0; i < 4; i++)
    o[(size_t)(d0 + ty + i * 8) * F_ + f0 + tx] = f2bf(tile[tx][ty + i * 8]);
}

__global__ __launch_bounds__(256) void r_rowsum(const float* __restrict__ r,
                                                const float* __restrict__ pm,
                                                float* __restrict__ rs) {
  int row = blockIdx.x;            // b*S + s
  int b = row >> 11, s = row & 2047;
  const float4* rp = (const float4*)(r + (size_t)row * S_);
  const float4* pp = (const float4*)(pm + (size_t)b * S_);
  int nv = (s >> 2) + 1;
  float acc = 0.f;
  for (int i = threadIdx.x; i < nv; i += 256) {
    float4 rv = rp[i];
    float4 pv = pp[i];
    int t0 = i << 2;
    #pragma unroll
    for (int j = 0; j < 4; j++) {
      int t = t0 + j;
      if (t <= s && (&pv.x)[j] != 0.f) acc += __expf((&rv.x)[j] - 16.f);
    }
  }
  for (int off = 1; off < 64; off <<= 1) acc += __shfl_xor(acc, off);
  __shared__ float wsum[4];
  int lane = threadIdx.x & 63, w = threadIdx.x >> 6;
  if (lane == 0) wsum[w] = acc;
  __syncthreads();
  if (threadIdx.x == 0) rs[row] = wsum[0] + wsum[1] + wsum[2] + wsum[3];
}

// =============== 256x256 / BK=64 / 8-wave pipelined GEMM engine ===============
// A: [M][K] row-major bf16, B: [N][K] row-major bf16 (B^T layout).
// LDS: 128 KB = 2 buffers x (A 256x64 + B 256x64) bf16, linear layout,
// XOR-swizzled reads (chunk ^= row&7) with inverse-swizzled global staging src.
// Schedule: 4 phases/K-tile, 2 barriers + 2 counted vmcnt waits per K-tile.

__device__ __forceinline__ void stageA(const u16* __restrict__ src, int ld, int h,
                                       u16* ldsA, int w, int l) {
  int base = ((w >> 2) * 128) + h * 64 + ((w & 3) * 16);
  int r = l >> 3, ch = (l & 7) ^ (l >> 3);
  #pragma unroll
  for (int i = 0; i < 2; i++) {
    int row = base + i * 8;
    stage16(src + (size_t)(row + r) * ld + ch * 8, ldsA + row * 64);
  }
}
__device__ __forceinline__ void stageB(const u16* __restrict__ src, int ld, int h,
                                       u16* ldsB, int w, int l) {
  int base = h * 128 + w * 16;
  int r = l >> 3, ch = (l & 7) ^ (l >> 3);
  #pragma unroll
  for (int i = 0; i < 2; i++) {
    int row = base + i * 8;
    stage16(src + (size_t)(row + r) * ld + ch * 8, ldsB + row * 64);
  }
}

__device__ __forceinline__ bf16x8 readfrag(const u16* lds, int row, int ks, int hi) {
  int c = ((ks << 6) + (hi << 4)) ^ ((row & 7) << 4);   // byte offset in row
  return *(const bf16x8*)((const char*)lds + row * 128 + c);
}

#define MFMA_QUAD(MB, KB)                                                        \
  __builtin_amdgcn_s_setprio(1);                                                 \
  _Pragma("unroll")                                                              \
  for (int m = 0; m < 4; m++)                                                    \
    _Pragma("unroll")                                                            \
    for (int n = 0; n < 4; n++)                                                  \
      acc[(MB) + m][n] = __builtin_amdgcn_mfma_f32_16x16x32_bf16(                \
          af[m], bfr[(KB) + n], acc[(MB) + m][n], 0, 0, 0);                      \
  __builtin_amdgcn_s_setprio(0);

#define SYNC_POINT()                                                             \
  __builtin_amdgcn_sched_barrier(0);                                             \
  __builtin_amdgcn_s_barrier();                                                  \
  __builtin_amdgcn_sched_barrier(0);

__device__ __forceinline__ void gemm256(const u16* __restrict__ A, int lda,
                                        const u16* __restrict__ B, int ldb,
                                        int nT, u16* lds, f32x4 acc[8][4]) {
  const int t = threadIdx.x, w = t >> 6, l = t & 63;
  const int wr = w >> 2, wc = w & 3;
  u16* A0 = lds;           u16* B0 = lds + 16384;
  u16* A1 = lds + 32768;   u16* B1 = lds + 49152;

  #pragma unroll
  for (int m = 0; m < 8; m++)
    #pragma unroll
    for (int n = 0; n < 4; n++)
      #pragma unroll
      for (int j = 0; j < 4; j++) acc[m][n][j] = 0.f;

  // prologue: B0(0),B1(0),Aalpha(0) [needed @P1] then Abeta(0),Aalpha(1)
  stageB(B, ldb, 0, B0, w, l);
  stageB(B, ldb, 1, B0, w, l);
  stageA(A, lda, 0, A0, w, l);
  stageA(A, lda, 1, A0, w, l);
  if (nT > 1) stageA(A + 64, lda, 0, A1, w, l);
  asm volatile("s_waitcnt vmcnt(4)" ::: "memory");
  SYNC_POINT()

  const int arow = wr * 128 + (l & 15), brow = wc * 64 + (l & 15), hi = l >> 4;

  for (int kt = 0; kt < nT; kt++) {
    u16* cA = (kt & 1) ? A1 : A0;
    u16* cB = (kt & 1) ? B1 : B0;
    u16* nA = (kt & 1) ? A0 : A1;
    u16* nB = (kt & 1) ? B0 : B1;
    const u16* An1 = A + (size_t)(kt + 1) * 64;
    const u16* Bn1 = B + (size_t)(kt + 1) * 64;
    const u16* An2 = A + (size_t)(kt + 2) * 64;
    const bool has1 = (kt + 1 < nT), has2 = (kt + 2 < nT);
    bf16x8 af[4], bfr[8];

    // P1: A(alpha,ks0) + B(ks0); issue B-half0(t+1)
    #pragma unroll
    for (int m = 0; m < 4; m++) af[m] = readfrag(cA, arow + m * 16, 0, hi);
    #pragma unroll
    for (int n = 0; n < 4; n++) bfr[n] = readfrag(cB, brow + n * 16, 0, hi);
    if (has1) stageB(Bn1, ldb, 0, nB, w, l);
    MFMA_QUAD(0, 0)

    // P2: A(alpha,ks1) + B(ks1); issue B-half1(t+1); wait covers Abeta(kt)
    #pragma unroll
    for (int m = 0; m < 4; m++) af[m] = readfrag(cA, arow + m * 16, 1, hi);
    #pragma unroll
    for (int n = 0; n < 4; n++) bfr[4 + n] = readfrag(cB, brow + n * 16, 1, hi);
    if (has1) {
      stageB(Bn1, ldb, 1, nB, w, l);
      asm volatile("s_waitcnt vmcnt(4)" ::: "memory");
    } else {
      asm volatile("s_waitcnt vmcnt(0)" ::: "memory");
    }
    SYNC_POINT()
    MFMA_QUAD(0, 4)

    // P3: A(beta,ks0), reuse B ks0; issue A-alpha(t+2) into freed alpha region
    #pragma unroll
    for (int m = 0; m < 4; m++) af[m] = readfrag(cA, arow + 64 + m * 16, 0, hi);
    if (has2) stageA(An2, lda, 0, cA, w, l);
    MFMA_QUAD(4, 0)

    // P4: A(beta,ks1); issue A-beta(t+1); wait covers B0/B1(t+1)
    #pragma unroll
    for (int m = 0; m < 4; m++) af[m] = readfrag(cA, arow + 64 + m * 16, 1, hi);
    if (has1) stageA(An1, lda, 1, nA, w, l);
    if (has1 && has2)  { asm volatile("s_waitcnt vmcnt(4)" ::: "memory"); }
    else if (has1)     { asm volatile("s_waitcnt vmcnt(2)" ::: "memory"); }
    else               { asm volatile("s_waitcnt vmcnt(0)" ::: "memory"); }
    SYNC_POINT()
    MFMA_QUAD(4, 4)
  }
}

// stage 256x256 f32 acc as bf16 through LDS in 64-row quarters; coalesced stores
__device__ __forceinline__ void store256_bf16(f32x4 acc[8][4], u16* smem,
                                              u16* dst, int ld) {
  int t = threadIdx.x, w = t >> 6, l = t & 63;
  int wr = w >> 2, wc = w & 3;
  #pragma unroll
  for (int q = 0; q < 4; q++) {
    __syncthreads();
    if (wr == (q >> 1)) {
      int mb = (q & 1) * 4;
      #pragma unroll
      for (int mm = 0; mm < 4; mm++)
        #pragma unroll
        for (int j = 0; j < 4; j++) {
          int row = mm * 16 + (l >> 4) * 4 + j;
          #pragma unroll
          for (int n = 0; n < 4; n++)
            smem[row * 264 + wc * 64 + n * 16 + (l & 15)] = f2bf(acc[mb + mm][n][j]);
        }
    }
    __syncthreads();
    #pragma unroll
    for (int i = 0; i < 4; i++) {
      int idx = i * 512 + t;            // 2048 u16x8 chunks = 64 rows x 32
      int row = idx >> 5, ch = idx & 31;
      *(u16x8*)(dst + (size_t)(q * 64 + row) * ld + ch * 8) =
          *(const u16x8*)(smem + row * 264 + ch * 8);
    }
  }
}

// ---------------- projection GEMM: q,k row-major; v computed transposed ----------------
__global__ __launch_bounds__(512, 2) void gemm_qkv(
    const u16* __restrict__ xb, const u16* __restrict__ Wt,
    u16* __restrict__ qb, u16* __restrict__ kb, u16* __restrict__ vT) {
  __shared__ __align__(16) u16 lds[65536];   // 128 KB
  int z = blockIdx.z;
  f32x4 acc[8][4];
  if (z < 2) {
    int m0 = blockIdx.x * 256, n0 = blockIdx.y * 256;
    gemm256(xb + (size_t)m0 * F_, F_,
            Wt + (size_t)z * D_ * F_ + (size_t)n0 * F_, F_, F_ / 64, lds, acc);
    store256_bf16(acc, lds, ((z == 0) ? qb : kb) + (size_t)m0 * D_ + n0, D_);
  } else {
    // v^T[d][s] = sum_f WvT[d][f] * x[s][f]
    int d0 = blockIdx.y * 256, s0g = blockIdx.x * 256;
    gemm256(Wt + 2ULL * D_ * F_ + (size_t)d0 * F_, F_,
            xb + (size_t)s0g * F_, F_, F_ / 64, lds, acc);
    int b = s0g >> 11, s0 = s0g & 2047;
    store256_bf16(acc, lds, vT + (size_t)b * D_ * S_ + (size_t)d0 * S_ + s0, S_);
  }
}

// ------- scores: P = keep ? exp(qk/32 + exp(r-16)/rs_r - 16) : 0; row sums -------
__global__ __launch_bounds__(512, 2) void attn_scores(
    const u16* __restrict__ qb, const u16* __restrict__ kb,
    const float* __restrict__ r_mat, const float* __restrict__ pm,
    const float* __restrict__ rs_r, u16* __restrict__ P,
    float* __restrict__ rowsum) {
  int mt = blockIdx.x, nt = blockIdx.y, b = blockIdx.z;
  if (nt > mt) return;
  __shared__ __align__(16) u16 lds[65536];
  int m0 = mt * 256, n0 = nt * 256;
  f32x4 acc[8][4];
  gemm256(qb + ((size_t)b * S_ + m0) * D_, D_,
          kb + ((size_t)b * S_ + n0) * D_, D_, D_ / 64, lds, acc);
  int t = threadIdx.x, w = t >> 6, l = t & 63;
  int wr = w >> 2, wc = w & 3;
  float* fs = (float*)lds;                  // 64 x 260 f32 staging
  const float* rb = r_mat + (size_t)b * S_ * S_;
  const float* pmp = pm + (size_t)b * S_ + n0;
  #pragma unroll
  for (int q = 0; q < 4; q++) {
    __syncthreads();
    if (wr == (q >> 1)) {
      int mb = (q & 1) * 4;
      #pragma unroll
      for (int mm = 0; mm < 4; mm++)
        #pragma unroll
        for (int j = 0; j < 4; j++) {
          int row = mm * 16 + (l >> 4) * 4 + j;
          #pragma unroll
          for (int n = 0; n < 4; n++)
            fs[row * 260 + wc * 64 + n * 16 + (l & 15)] = acc[mb + mm][n][j];
        }
    }
    __syncthreads();
    int row = t >> 3, cg = t & 7;
    int srow = m0 + q * 64 + row;
    float invr = 1.f / rs_r[b * S_ + srow];
    const float* rrow = rb + (size_t)srow * S_ + n0 + cg * 32;
    u16* prow = P + (size_t)b * S_ * S_ + (size_t)srow * S_ + n0 + cg * 32;
    const float* fsc = fs + row * 260 + cg * 32;
    float rsum = 0.f;
    #pragma unroll
    for (int cc = 0; cc < 4; cc++) {
      int ch = (cg + cc) & 3;               // stagger to dodge LDS bank collisions
      f32x4 q0 = *(const f32x4*)(fsc + ch * 8);
      f32x4 q1 = *(const f32x4*)(fsc + ch * 8 + 4);
      f32x4 r0 = *(const f32x4*)(rrow + ch * 8);
      f32x4 r1 = *(const f32x4*)(rrow + ch * 8 + 4);
      f32x4 p0 = *(const f32x4*)(pmp + cg * 32 + ch * 8);
      f32x4 p1 = *(const f32x4*)(pmp + cg * 32 + ch * 8 + 4);
      u16x8 o;
      #pragma unroll
      for (int k = 0; k < 8; k++) {
        int tc = n0 + cg * 32 + ch * 8 + k;
        float rv = (k < 4) ? r0[k] : r1[k - 4];
        float pmv = (k < 4) ? p0[k] : p1[k - 4];
        float qk = (k < 4) ? q0[k] : q1[k - 4];
        bool keep = (tc <= srow) && (pmv != 0.f);
        float rsm = __expf(rv - 16.f) * invr;
        float e = keep ? __expf(fmaf(qk, 0.03125f, rsm - 16.f)) : 0.f;
        u16 pb = f2bf(e); o[k] = pb; rsum += bf2f(pb);
      }
      *(u16x8*)(prow + ch * 8) = o;
    }
    for (int off = 1; off < 8; off <<= 1) rsum += __shfl_xor(rsum, off);
    if ((t & 7) == 0) atomicAdd(&rowsum[b * S_ + srow], rsum);
  }
}

// ---------------- PV: out = (P @ V) / rowsum ----------------
__global__ __launch_bounds__(512, 2) void attn_pv(
    const u16* __restrict__ P, const u16* __restrict__ vT,
    const float* __restrict__ rowsum, float* __restrict__ out) {
  __shared__ __align__(16) u16 lds[65536];
  int mt = blockIdx.x, dt = blockIdx.y, b = blockIdx.z;
  int m0 = mt * 256, n0 = dt * 256;
  int kmax = m0 + 256;                      // causal support, 256-rounded
  f32x4 acc[8][4];
  gemm256(P + ((size_t)b * S_ + m0) * S_, S_,
          vT + ((size_t)b * D_ + n0) * S_, S_, kmax / 64, lds, acc);
  int t = threadIdx.x, w = t >> 6, l = t & 63;
  int wr = w >> 2, wc = w & 3;
  float* fs = (float*)lds;
  #pragma unroll
  for (int q = 0; q < 4; q++) {
    __syncthreads();
    if (wr == (q >> 1)) {
      int mb = (q & 1) * 4;
      #pragma unroll
      for (int mm = 0; mm < 4; mm++)
        #pragma unroll
        for (int j = 0; j < 4; j++) {
          int row = mm * 16 + (l >> 4) * 4 + j;
          float inv = 1.f / rowsum[b * S_ + m0 + q * 64 + row];
          #pragma unroll
          for (int n = 0; n < 4; n++)
            fs[row * 260 + wc * 64 + n * 16 + (l & 15)] = acc[mb + mm][n][j] * inv;
        }
    }
    __syncthreads();
    #pragma unroll
    for (int i = 0; i < 8; i++) {
      int idx = i * 512 + t;                // 4096 float4 = 64 rows x 64
      int row = idx >> 6, c4 = (idx & 63) << 2;
      *(float4*)(out + ((size_t)b * S_ + m0 + q * 64 + row) * D_ + n0 + c4) =
          *(const float4*)(fs + row * 260 + c4);
    }
  }
}

// ---------------- launch ----------------
extern "C" void kernel_launch(void* const* d_in, const int* in_sizes, int n_in,
                              void* d_out, int out_size, void* d_ws, size_t ws_size,
                              hipStream_t stream) {
  const float* x     = (const float*)d_in[0];
  const float* r_mat = (const float*)d_in[1];
  const float* pm    = (const float*)d_in[3];
  const float* Wq    = (const float*)d_in[4];
  const float* Wk    = (const float*)d_in[5];
  const float* Wv    = (const float*)d_in[6];
  float* out = (float*)d_out;
  char* ws = (char*)d_ws;

  u16*   qb     = (u16*)(ws + 0);
  u16*   kb     = (u16*)(ws + 33554432ULL);
  u16*   vT     = (u16*)(ws + 67108864ULL);
  float* rs_r   = (float*)(ws + 100663296ULL);
  float* rowsum = (float*)(ws + 100728832ULL);
  u16*   P      = (u16*)(ws + 100794368ULL);   // aliases xb (dead after gemm_qkv)
  u16*   xb     = (u16*)(ws + 100794368ULL);
  u16*   Wt     = (u16*)(ws + 134348800ULL);

  cast_x<<<dim3(2048), dim3(256), 0, stream>>>(x, xb, (B_ * S_ * F_) / 4);
  transW<<<dim3(32, 32, 3), dim3(256), 0, stream>>>(Wq, Wk, Wv, Wt);
  r_rowsum<<<dim3(B_ * S_), dim3(256), 0, stream>>>(r_mat, pm, rs_r);
  gemm_qkv<<<dim3(64, 4, 3), dim3(512), 0, stream>>>(xb, Wt, qb, kb, vT);
  hipMemsetAsync(rowsum, 0, B_ * S_ * sizeof(float), stream);
  attn_scores<<<dim3(8, 8, 8), dim3(512), 0, stream>>>(qb, kb, r_mat, pm, rs_r, P, rowsum);
  attn_pv<<<dim3(8, 4, 8), dim3(512), 0, stream>>>(P, vT, rowsum, out);
}